// Round 1
// baseline (4119.055 us; speedup 1.0000x reference)
//
#include <hip/hip_runtime.h>
#include <math.h>

#define NN 50000
#define NE 800000
#define DD 64
#define NGRAPH 100
#define NPG 500

// ---------------- setup kernels ----------------

__global__ void k_deg(const int* __restrict__ col, int* __restrict__ degi) {
    int e = blockIdx.x * blockDim.x + threadIdx.x;
    if (e < NE) atomicAdd(&degi[col[e]], 1);
}

__global__ void k_dh(const int* __restrict__ degi, float* __restrict__ dh) {
    int i = blockIdx.x * blockDim.x + threadIdx.x;
    if (i < NN) {
        int d = degi[i];
        dh[i] = d > 0 ? (float)(1.0 / sqrt((double)d)) : 0.0f;
    }
}

// single-block exclusive scan of degi[NN] -> off[NN]
__global__ void k_scan(const int* __restrict__ degi, int* __restrict__ off) {
    __shared__ int buf[2][1024];
    __shared__ int carry;
    int tid = threadIdx.x;
    if (tid == 0) carry = 0;
    __syncthreads();
    for (int base = 0; base < NN; base += 1024) {
        int v = (base + tid < NN) ? degi[base + tid] : 0;
        int cur = 0;
        buf[0][tid] = v;
        __syncthreads();
        for (int s = 1; s < 1024; s <<= 1) {
            int val = buf[cur][tid];
            if (tid >= s) val += buf[cur][tid - s];
            buf[cur ^ 1][tid] = val;
            cur ^= 1;
            __syncthreads();
        }
        if (base + tid < NN) off[base + tid] = carry + buf[cur][tid] - v;
        __syncthreads();
        if (tid == 0) carry += buf[cur][1023];
        __syncthreads();
    }
}

__global__ void k_fill(const int* __restrict__ row, const int* __restrict__ col,
                       const float* __restrict__ dh, const int* __restrict__ off,
                       int* __restrict__ cursor, int* __restrict__ csr_r,
                       float* __restrict__ csr_w) {
    int e = blockIdx.x * blockDim.x + threadIdx.x;
    if (e >= NE) return;
    int r = row[e], c = col[e];
    int pos = off[c] + atomicAdd(&cursor[c], 1);
    csr_r[pos] = r;
    csr_w[pos] = dh[r] * dh[c];
}

// ---------------- phase 1 (F = 64) ----------------
// T1 = -A x ; acc init: hacc[n][s*64+f] = c0[s]*0.5*x + c1[s]*T1
__global__ __launch_bounds__(256) void k_p1_init(
    const float* __restrict__ x, const int* __restrict__ off, const int* __restrict__ degi,
    const int* __restrict__ csr_r, const float* __restrict__ csr_w,
    float* __restrict__ T1, float* __restrict__ hacc,
    float c00, float c01, float c02, float c03,
    float c10, float c11, float c12, float c13) {
    int lane = threadIdx.x & 63;
    int node = blockIdx.x * 4 + (threadIdx.x >> 6);
    if (node >= NN) return;
    int s = off[node], cnt = degi[node];
    float g = 0.f;
    for (int i = 0; i < cnt; ++i) {
        int r = csr_r[s + i];
        float w = csr_w[s + i];
        g += w * x[r * DD + lane];
    }
    float t1 = -g;
    float x0 = x[node * DD + lane];
    T1[node * DD + lane] = t1;
    float* hp = hacc + node * 256 + lane;
    hp[0]   = c00 * 0.5f * x0 + c10 * t1;
    hp[64]  = c01 * 0.5f * x0 + c11 * t1;
    hp[128] = c02 * 0.5f * x0 + c12 * t1;
    hp[192] = c03 * 0.5f * x0 + c13 * t1;
}

// Tnext = -2 A Tcur - Tprev ; hacc[n][s*64+f] += ck[s]*Tnext
// NOTE: Tprev/Tnext may alias (elementwise in-place) -> no __restrict__ on them.
__global__ __launch_bounds__(256) void k_p1_step(
    const float* __restrict__ Tcur, const float* Tprev, float* Tnext,
    const int* __restrict__ off, const int* __restrict__ degi,
    const int* __restrict__ csr_r, const float* __restrict__ csr_w,
    float* __restrict__ hacc,
    float ck0, float ck1, float ck2, float ck3) {
    int lane = threadIdx.x & 63;
    int node = blockIdx.x * 4 + (threadIdx.x >> 6);
    if (node >= NN) return;
    int s = off[node], cnt = degi[node];
    float g = 0.f;
    for (int i = 0; i < cnt; ++i) {
        int r = csr_r[s + i];
        float w = csr_w[s + i];
        g += w * Tcur[r * DD + lane];
    }
    float t = -2.f * g - Tprev[node * DD + lane];
    Tnext[node * DD + lane] = t;
    float* hp = hacc + node * 256 + lane;
    hp[0]   += ck0 * t;
    hp[64]  += ck1 * t;
    hp[128] += ck2 * t;
    hp[192] += ck3 * t;
}

__global__ void k_abs(float* __restrict__ a, int n) {
    int i = blockIdx.x * blockDim.x + threadIdx.x;
    if (i < n) a[i] = fabsf(a[i]);
}

// ---------------- phase 2 (F = 192: s1 groups 0,1,2 of h) ----------------
// acc2 layout [NN,384]: [0:64)=(s2=1,s1=0) [64:192)=(s2=2,s1=0..1) [192:384)=(s2=3,s1=0..2)
__global__ __launch_bounds__(192) void k_p2_init(
    const float* __restrict__ h /*[NN,256]*/,
    const int* __restrict__ off, const int* __restrict__ degi,
    const int* __restrict__ csr_r, const float* __restrict__ csr_w,
    float* __restrict__ T1 /*[NN,192]*/, float* __restrict__ acc2 /*[NN,384]*/,
    float c01, float c02, float c03,
    float c11, float c12, float c13) {
    int f = threadIdx.x;          // 0..191
    int node = blockIdx.x;
    int s = off[node], cnt = degi[node];
    float g = 0.f;
    for (int i = 0; i < cnt; ++i) {
        int r = csr_r[s + i];
        float w = csr_w[s + i];
        g += w * h[r * 256 + f];
    }
    float t1 = -g;
    float h0 = h[node * 256 + f];
    T1[node * 192 + f] = t1;
    float* ap = acc2 + node * 384;
    if (f < 64)  ap[f]        = c01 * 0.5f * h0 + c11 * t1;
    if (f < 128) ap[64 + f]   = c02 * 0.5f * h0 + c12 * t1;
    ap[192 + f] = c03 * 0.5f * h0 + c13 * t1;
}

__global__ __launch_bounds__(192) void k_p2_step(
    const float* __restrict__ Tcur /*[NN,192]*/, const float* Tprev, int ldPrev,
    float* Tnext,
    const int* __restrict__ off, const int* __restrict__ degi,
    const int* __restrict__ csr_r, const float* __restrict__ csr_w,
    float* __restrict__ acc2,
    float ck1, float ck2, float ck3) {
    int f = threadIdx.x;
    int node = blockIdx.x;
    int s = off[node], cnt = degi[node];
    float g = 0.f;
    for (int i = 0; i < cnt; ++i) {
        int r = csr_r[s + i];
        float w = csr_w[s + i];
        g += w * Tcur[r * 192 + f];
    }
    float t = -2.f * g - Tprev[node * ldPrev + f];
    Tnext[node * 192 + f] = t;
    float* ap = acc2 + node * 384;
    if (f < 64)  ap[f]      += ck1 * t;
    if (f < 128) ap[64 + f] += ck2 * t;
    ap[192 + f] += ck3 * t;
}

// ---------------- moments ----------------
// feat col c: [0,64) -> x, [64,320) -> h (abs already applied), [320,704) -> |acc2|
__global__ void k_moments(const float* __restrict__ x, const float* __restrict__ h,
                          const float* __restrict__ acc2, float* __restrict__ out) {
    int g = blockIdx.y;
    int col = blockIdx.x * 256 + threadIdx.x;
    if (col >= 704) return;
    const float* src;
    int ld, c0;
    bool doabs = false;
    if (col < 64)       { src = x;    ld = 64;  c0 = col; }
    else if (col < 320) { src = h;    ld = 256; c0 = col - 64; }
    else                { src = acc2; ld = 384; c0 = col - 320; doabs = true; }
    double s1 = 0, s2 = 0, s3 = 0, s4 = 0;
    int base = g * NPG;
    for (int i = 0; i < NPG; ++i) {
        float vf = src[(size_t)(base + i) * ld + c0];
        if (doabs) vf = fabsf(vf);
        double v = (double)vf;
        double v2 = v * v;
        s1 += v; s2 += v2; s3 += v2 * v; s4 += v2 * v2;
    }
    double n = (double)NPG;
    double mu = s1 / n;
    double E2 = s2 / n, E3 = s3 / n, E4 = s4 / n;
    double m2 = E2 - mu * mu;
    double m3 = E3 - 3.0 * mu * E2 + 2.0 * mu * mu * mu;
    double m4 = E4 - 4.0 * mu * E3 + 6.0 * mu * mu * E2 - 3.0 * mu * mu * mu * mu;
    float m2f = (float)m2;
    float skew = 0.f, kurt = -3.f;
    if (m2f > 0.f) {
        double sk = m3 / (m2 * sqrt(m2));
        skew = (float)sk;
        if (skew > 1e15f) skew = 0.f;
        double ku = m4 / (m2 * m2) - 3.0;
        kurt = (float)ku;
        if (kurt > 1e15f) kurt = -3.f;
    }
    size_t ob = (size_t)g * 2816 + col;
    out[ob]        = (float)mu;
    out[ob + 704]  = m2f;
    out[ob + 1408] = skew;
    out[ob + 2112] = kurt;
}

// ---------------- host ----------------

extern "C" void kernel_launch(void* const* d_in, const int* in_sizes, int n_in,
                              void* d_out, int out_size, void* d_ws, size_t ws_size,
                              hipStream_t stream) {
    const float* x = (const float*)d_in[0];
    const int* ei  = (const int*)d_in[1];
    const int* row = ei;
    const int* col = ei + NE;
    float* out = (float*)d_out;

    // Chebyshev coefficients [17][4] (double, matches numpy path)
    float C[17][4];
    {
        const int Nc = 17;
        const int scales[4] = {2, 4, 8, 16};
        for (int si = 0; si < 4; ++si) {
            double ker[17];
            for (int j = 0; j < Nc; ++j) {
                double num = cos(M_PI * (j + 0.5) / Nc);
                double xs = num + 1.0;       // a1*num + a2, a1=a2=1
                double b = 1.0 - xs;         // = -num
                double v = pow(b, (double)(scales[si] / 2)) - pow(b, (double)scales[si]);
                if (v < 0) v = 0;
                ker[j] = sqrt(v);
            }
            for (int o = 0; o < Nc; ++o) {
                double acc = 0;
                for (int j = 0; j < Nc; ++j) acc += ker[j] * cos(M_PI * o * (j + 0.5) / Nc);
                C[o][si] = (float)(2.0 / Nc * acc);
            }
        }
    }

    // workspace carve (~212 MB)
    char* p = (char*)d_ws;
    auto alloc = [&](size_t bytes) -> void* {
        void* r = (void*)p;
        p += (bytes + 255) & ~(size_t)255;
        return r;
    };
    int*   degi   = (int*)alloc((size_t)NN * 4);
    float* dh     = (float*)alloc((size_t)NN * 4);
    int*   off    = (int*)alloc((size_t)NN * 4);
    int*   cursor = (int*)alloc((size_t)NN * 4);
    int*   csr_r  = (int*)alloc((size_t)NE * 4);
    float* csr_w  = (float*)alloc((size_t)NE * 4);
    float* hacc   = (float*)alloc((size_t)NN * 256 * 4);
    float* tA     = (float*)alloc((size_t)NN * 192 * 4);
    float* tB     = (float*)alloc((size_t)NN * 192 * 4);
    float* acc2   = (float*)alloc((size_t)NN * 384 * 4);
    if ((size_t)(p - (char*)d_ws) > ws_size) return;  // workspace too small: fail loudly

    hipMemsetAsync(degi, 0, (size_t)NN * 4, stream);
    hipMemsetAsync(cursor, 0, (size_t)NN * 4, stream);

    k_deg <<<(NE + 255) / 256, 256, 0, stream>>>(col, degi);
    k_dh  <<<(NN + 255) / 256, 256, 0, stream>>>(degi, dh);
    k_scan<<<1, 1024, 0, stream>>>(degi, off);
    k_fill<<<(NE + 255) / 256, 256, 0, stream>>>(row, col, dh, off, cursor, csr_r, csr_w);

    // ---- phase 1 ----
    k_p1_init<<<(NN + 3) / 4, 256, 0, stream>>>(x, off, degi, csr_r, csr_w, tA, hacc,
        C[0][0], C[0][1], C[0][2], C[0][3],
        C[1][0], C[1][1], C[1][2], C[1][3]);
    {
        const float* Tprev = x;
        const float* Tcur  = tA;
        for (int k = 2; k <= 16; ++k) {
            float* Tnext = (k == 2) ? tB : (float*)Tprev;  // in-place overwrite of T_{k-2}
            k_p1_step<<<(NN + 3) / 4, 256, 0, stream>>>(Tcur, Tprev, Tnext,
                off, degi, csr_r, csr_w, hacc,
                C[k][0], C[k][1], C[k][2], C[k][3]);
            Tprev = Tcur;
            Tcur  = Tnext;
        }
    }

    k_abs<<<(NN * 256 + 255) / 256, 256, 0, stream>>>(hacc, NN * 256);

    // ---- phase 2 (F=192) ----
    k_p2_init<<<NN, 192, 0, stream>>>(hacc, off, degi, csr_r, csr_w, tA, acc2,
        C[0][1], C[0][2], C[0][3],
        C[1][1], C[1][2], C[1][3]);
    {
        const float* Tprev = hacc;
        int ldprev = 256;
        const float* Tcur = tA;
        for (int k = 2; k <= 16; ++k) {
            float* Tnext = (k == 2) ? tB : (float*)Tprev;
            k_p2_step<<<NN, 192, 0, stream>>>(Tcur, Tprev, ldprev, Tnext,
                off, degi, csr_r, csr_w, acc2,
                C[k][1], C[k][2], C[k][3]);
            Tprev = Tcur;
            Tcur  = Tnext;
            ldprev = 192;
        }
    }

    // ---- moments ----
    dim3 mg(3, NGRAPH);
    k_moments<<<mg, 256, 0, stream>>>(x, hacc, acc2, out);
}

// Round 3
// 2840.139 us; speedup vs baseline: 1.4503x; 1.4503x over previous
//
#include <hip/hip_runtime.h>
#include <math.h>

#define NN 50000
#define NE 800000
#define NGRAPH 100
#define NPG 500

typedef _Float16 f16;

// ---------------- setup kernels ----------------

__global__ void k_deg(const int* __restrict__ col, int* __restrict__ degi) {
    int e = blockIdx.x * blockDim.x + threadIdx.x;
    if (e < NE) atomicAdd(&degi[col[e]], 1);
}

__global__ void k_dh(const int* __restrict__ degi, float* __restrict__ dh) {
    int i = blockIdx.x * blockDim.x + threadIdx.x;
    if (i < NN) {
        int d = degi[i];
        dh[i] = d > 0 ? (float)(1.0 / sqrt((double)d)) : 0.0f;
    }
}

__global__ void k_scan(const int* __restrict__ degi, int* __restrict__ off) {
    __shared__ int buf[2][1024];
    __shared__ int carry;
    int tid = threadIdx.x;
    if (tid == 0) carry = 0;
    __syncthreads();
    for (int base = 0; base < NN; base += 1024) {
        int v = (base + tid < NN) ? degi[base + tid] : 0;
        int cur = 0;
        buf[0][tid] = v;
        __syncthreads();
        for (int s = 1; s < 1024; s <<= 1) {
            int val = buf[cur][tid];
            if (tid >= s) val += buf[cur][tid - s];
            buf[cur ^ 1][tid] = val;
            cur ^= 1;
            __syncthreads();
        }
        if (base + tid < NN) off[base + tid] = carry + buf[cur][tid] - v;
        __syncthreads();
        if (tid == 0) carry += buf[cur][1023];
        __syncthreads();
    }
}

__global__ void k_fill(const int* __restrict__ row, const int* __restrict__ col,
                       const float* __restrict__ dh, const int* __restrict__ off,
                       int* __restrict__ cursor, int* __restrict__ csr_r,
                       float* __restrict__ csr_w) {
    int e = blockIdx.x * blockDim.x + threadIdx.x;
    if (e >= NE) return;
    int r = row[e], c = col[e];
    int pos = off[c] + atomicAdd(&cursor[c], 1);
    csr_r[pos] = r;
    csr_w[pos] = dh[r] * dh[c];
}

// ---------------- recurrence kernels (fp32, F=64, dual-write f16 archive) ----

// T1 = -A·src
__global__ __launch_bounds__(256) void k_init(
    const float* __restrict__ src, const int* __restrict__ off,
    const int* __restrict__ degi, const int* __restrict__ csr_r,
    const float* __restrict__ csr_w, float* __restrict__ Tout,
    f16* __restrict__ slot) {
    int f = threadIdx.x & 63;
    int node = blockIdx.x * 4 + (threadIdx.x >> 6);
    if (node >= NN) return;
    int s = off[node], e = s + degi[node];
    float g = 0.f;
    int i = s;
    for (; i + 3 < e; i += 4) {
        int r0 = csr_r[i], r1 = csr_r[i + 1], r2 = csr_r[i + 2], r3 = csr_r[i + 3];
        float w0 = csr_w[i], w1 = csr_w[i + 1], w2 = csr_w[i + 2], w3 = csr_w[i + 3];
        g += w0 * src[r0 * 64 + f] + w1 * src[r1 * 64 + f]
           + w2 * src[r2 * 64 + f] + w3 * src[r3 * 64 + f];
    }
    for (; i < e; ++i) g += csr_w[i] * src[csr_r[i] * 64 + f];
    float t = -g;
    Tout[node * 64 + f] = t;
    slot[node * 64 + f] = (f16)t;
}

// Tnext = -2·A·Tcur - Tprev   (Tprev/Tnext may alias elementwise in-place)
__global__ __launch_bounds__(256) void k_step(
    const float* __restrict__ Tcur, const float* Tprev, float* Tnext,
    f16* __restrict__ slot, const int* __restrict__ off,
    const int* __restrict__ degi, const int* __restrict__ csr_r,
    const float* __restrict__ csr_w) {
    int f = threadIdx.x & 63;
    int node = blockIdx.x * 4 + (threadIdx.x >> 6);
    if (node >= NN) return;
    int s = off[node], e = s + degi[node];
    float g = 0.f;
    int i = s;
    for (; i + 3 < e; i += 4) {
        int r0 = csr_r[i], r1 = csr_r[i + 1], r2 = csr_r[i + 2], r3 = csr_r[i + 3];
        float w0 = csr_w[i], w1 = csr_w[i + 1], w2 = csr_w[i + 2], w3 = csr_w[i + 3];
        g += w0 * Tcur[r0 * 64 + f] + w1 * Tcur[r1 * 64 + f]
           + w2 * Tcur[r2 * 64 + f] + w3 * Tcur[r3 * 64 + f];
    }
    for (; i < e; ++i) g += csr_w[i] * Tcur[csr_r[i] * 64 + f];
    float t = -2.f * g - Tprev[node * 64 + f];
    Tnext[node * 64 + f] = t;
    slot[node * 64 + f] = (f16)t;
}

// ---------------- combine: acc planes from 8 archived T_k ----------------

struct CombCfg {
    float c0[4];      // coeff for src0 term (×0.5 applied host-side)  [FIRST only]
    float ck[4][8];   // coeffs for pool slots 0..7
    int   plane[4];   // target plane index (stride NN*64) in accb
};

template <int NT, bool FIRST, bool ABS>
__global__ __launch_bounds__(256) void k_combine(
    const float* __restrict__ src0, const f16* __restrict__ pool,
    float* __restrict__ accb, CombCfg cfg) {
    int f = threadIdx.x & 63;
    int node = blockIdx.x * 4 + (threadIdx.x >> 6);
    if (node >= NN) return;
    int idx = node * 64 + f;
    float tv[8];
#pragma unroll
    for (int j = 0; j < 8; ++j) tv[j] = (float)pool[(size_t)j * NN * 64 + idx];
    float s0 = FIRST ? src0[idx] : 0.f;
#pragma unroll
    for (int t = 0; t < NT; ++t) {
        size_t o = (size_t)cfg.plane[t] * NN * 64 + idx;
        float a = FIRST ? cfg.c0[t] * s0 : accb[o];
#pragma unroll
        for (int j = 0; j < 8; ++j) a += cfg.ck[t][j] * tv[j];
        if (ABS) a = fabsf(a);
        accb[o] = a;
    }
}

// ---------------- moments ----------------
// cols: [0,64)->x, [64,320)->hacc planes (abs'ed), [320,704)->acc2 planes (abs'ed)
__global__ void k_moments(const float* __restrict__ x, const float* __restrict__ hacc,
                          const float* __restrict__ acc2, float* __restrict__ out) {
    int g = blockIdx.y;
    int col = blockIdx.x * 256 + threadIdx.x;
    if (col >= 704) return;
    const float* src;
    int c0;
    if (col < 64)       { src = x;    c0 = col; }
    else if (col < 320) { int p = (col - 64) >> 6;  src = hacc + (size_t)p * NN * 64; c0 = (col - 64) & 63; }
    else                { int p = (col - 320) >> 6; src = acc2 + (size_t)p * NN * 64; c0 = (col - 320) & 63; }
    double s1 = 0, s2 = 0, s3 = 0, s4 = 0;
    int base = g * NPG;
    for (int i = 0; i < NPG; ++i) {
        double v = (double)src[(size_t)(base + i) * 64 + c0];
        double v2 = v * v;
        s1 += v; s2 += v2; s3 += v2 * v; s4 += v2 * v2;
    }
    double n = (double)NPG;
    double mu = s1 / n;
    double E2 = s2 / n, E3 = s3 / n, E4 = s4 / n;
    double m2 = E2 - mu * mu;
    double m3 = E3 - 3.0 * mu * E2 + 2.0 * mu * mu * mu;
    double m4 = E4 - 4.0 * mu * E3 + 6.0 * mu * mu * E2 - 3.0 * mu * mu * mu * mu;
    float m2f = (float)m2;
    float skew = 0.f, kurt = -3.f;
    if (m2f > 0.f) {
        skew = (float)(m3 / (m2 * sqrt(m2)));
        if (skew > 1e15f) skew = 0.f;
        kurt = (float)(m4 / (m2 * m2) - 3.0);
        if (kurt > 1e15f) kurt = -3.f;
    }
    size_t ob = (size_t)g * 2816 + col;
    out[ob]        = (float)mu;
    out[ob + 704]  = m2f;
    out[ob + 1408] = skew;
    out[ob + 2112] = kurt;
}

// ---------------- host ----------------

extern "C" void kernel_launch(void* const* d_in, const int* in_sizes, int n_in,
                              void* d_out, int out_size, void* d_ws, size_t ws_size,
                              hipStream_t stream) {
    const float* x = (const float*)d_in[0];
    const int* ei  = (const int*)d_in[1];
    const int* row = ei;
    const int* col = ei + NE;
    float* out = (float*)d_out;

    // Chebyshev coefficients [17][4], double precision (matches numpy)
    float C[17][4];
    {
        const int Nc = 17;
        const int scales[4] = {2, 4, 8, 16};
        for (int si = 0; si < 4; ++si) {
            double ker[17];
            for (int j = 0; j < Nc; ++j) {
                double num = cos(M_PI * (j + 0.5) / Nc);
                double b = -num;   // 1 - (num + 1)
                double v = pow(b, (double)(scales[si] / 2)) - pow(b, (double)scales[si]);
                if (v < 0) v = 0;
                ker[j] = sqrt(v);
            }
            for (int o = 0; o < Nc; ++o) {
                double acc = 0;
                for (int j = 0; j < Nc; ++j) acc += ker[j] * cos(M_PI * o * (j + 0.5) / Nc);
                C[o][si] = (float)(2.0 / Nc * acc);
            }
        }
    }

    // workspace carve (212.0 MB)
    char* p = (char*)d_ws;
    auto alloc = [&](size_t bytes) -> void* {
        void* r = (void*)p;
        p += (bytes + 255) & ~(size_t)255;
        return r;
    };
    int*   degi   = (int*)alloc((size_t)NN * 4);
    float* dh     = (float*)alloc((size_t)NN * 4);
    int*   off    = (int*)alloc((size_t)NN * 4);
    int*   cursor = (int*)alloc((size_t)NN * 4);
    int*   csr_r  = (int*)alloc((size_t)NE * 4);
    float* csr_w  = (float*)alloc((size_t)NE * 4);
    f16*   pool   = (f16*)alloc((size_t)8 * NN * 64 * 2);    // 51.2 MB archive
    float* tA     = (float*)alloc((size_t)NN * 64 * 4);      // 12.8 MB
    float* tB     = (float*)alloc((size_t)NN * 64 * 4);      // 12.8 MB
    float* hacc   = (float*)alloc((size_t)4 * NN * 64 * 4);  // 51.2 MB |h| planes
    float* acc2   = (float*)alloc((size_t)6 * NN * 64 * 4);  // 76.8 MB |d2| planes
    if ((size_t)(p - (char*)d_ws) > ws_size) return;

    hipMemsetAsync(degi, 0, (size_t)NN * 4, stream);
    hipMemsetAsync(cursor, 0, (size_t)NN * 4, stream);

    k_deg <<<(NE + 255) / 256, 256, 0, stream>>>(col, degi);
    k_dh  <<<(NN + 255) / 256, 256, 0, stream>>>(degi, dh);
    k_scan<<<1, 1024, 0, stream>>>(degi, off);
    k_fill<<<(NE + 255) / 256, 256, 0, stream>>>(row, col, dh, off, cursor, csr_r, csr_w);

    const int g1 = (NN + 3) / 4;
    auto slot = [&](int k) { return pool + (size_t)((k - 1) & 7) * NN * 64; };

    // ============ phase 1: recurrence on x, archive T_1..T_16, combine to |h| ====
    k_init<<<g1, 256, 0, stream>>>(x, off, degi, csr_r, csr_w, tA, slot(1));
    {
        const float* Tprev = x;
        const float* Tcur  = tA;
        for (int k = 2; k <= 16; ++k) {
            float* Tnext = (k == 2) ? tB : (float*)Tprev;
            k_step<<<g1, 256, 0, stream>>>(Tcur, Tprev, Tnext, slot(k),
                                           off, degi, csr_r, csr_w);
            Tprev = Tcur;
            Tcur  = Tnext;
            if (k == 8) {   // combine T1..T8 (+ c0 term on x)
                CombCfg cfg;
                for (int t = 0; t < 4; ++t) {
                    cfg.c0[t] = 0.5f * C[0][t];
                    cfg.plane[t] = t;
                    for (int j = 0; j < 8; ++j) cfg.ck[t][j] = C[j + 1][t];
                }
                k_combine<4, true, false><<<g1, 256, 0, stream>>>(x, pool, hacc, cfg);
            }
        }
        {   // combine T9..T16 + abs
            CombCfg cfg;
            for (int t = 0; t < 4; ++t) {
                cfg.c0[t] = 0.f;
                cfg.plane[t] = t;
                for (int j = 0; j < 8; ++j) cfg.ck[t][j] = C[j + 9][t];
            }
            k_combine<4, false, true><<<g1, 256, 0, stream>>>(nullptr, pool, hacc, cfg);
        }
    }

    // ============ phase 2: 3 independent groups (s1=0,1,2) ============
    // targets per group: (s2 scale index, acc plane)
    const int ntarg[3] = {3, 2, 1};
    const int tscale[3][3] = {{1, 2, 3}, {2, 3, 0}, {3, 0, 0}};
    const int tplane[3][3] = {{0, 1, 3}, {2, 4, 0}, {5, 0, 0}};

    for (int gidx = 0; gidx < 3; ++gidx) {
        const float* hsrc = hacc + (size_t)gidx * NN * 64;
        k_init<<<g1, 256, 0, stream>>>(hsrc, off, degi, csr_r, csr_w, tA, slot(1));
        const float* Tprev = hsrc;
        const float* Tcur  = tA;
        int nt = ntarg[gidx];
        for (int k = 2; k <= 16; ++k) {
            float* Tnext = (k == 2) ? tB : (float*)Tprev;
            k_step<<<g1, 256, 0, stream>>>(Tcur, Tprev, Tnext, slot(k),
                                           off, degi, csr_r, csr_w);
            Tprev = Tcur;
            Tcur  = Tnext;
            if (k == 8) {
                CombCfg cfg;
                for (int t = 0; t < nt; ++t) {
                    int si = tscale[gidx][t];
                    cfg.c0[t] = 0.5f * C[0][si];
                    cfg.plane[t] = tplane[gidx][t];
                    for (int j = 0; j < 8; ++j) cfg.ck[t][j] = C[j + 1][si];
                }
                if (nt == 3) k_combine<3, true, false><<<g1, 256, 0, stream>>>(hsrc, pool, acc2, cfg);
                if (nt == 2) k_combine<2, true, false><<<g1, 256, 0, stream>>>(hsrc, pool, acc2, cfg);
                if (nt == 1) k_combine<1, true, false><<<g1, 256, 0, stream>>>(hsrc, pool, acc2, cfg);
            }
        }
        {
            CombCfg cfg;
            for (int t = 0; t < nt; ++t) {
                int si = tscale[gidx][t];
                cfg.c0[t] = 0.f;
                cfg.plane[t] = tplane[gidx][t];
                for (int j = 0; j < 8; ++j) cfg.ck[t][j] = C[j + 9][si];
            }
            if (nt == 3) k_combine<3, false, true><<<g1, 256, 0, stream>>>(nullptr, pool, acc2, cfg);
            if (nt == 2) k_combine<2, false, true><<<g1, 256, 0, stream>>>(nullptr, pool, acc2, cfg);
            if (nt == 1) k_combine<1, false, true><<<g1, 256, 0, stream>>>(nullptr, pool, acc2, cfg);
        }
    }

    // ---- moments ----
    dim3 mg(3, NGRAPH);
    k_moments<<<mg, 256, 0, stream>>>(x, hacc, acc2, out);
}